// Round 2
// baseline (1240.940 us; speedup 1.0000x reference)
//
#include <hip/hip_runtime.h>

#define B_DIM 8
#define CIN   32
#define COUT  64
#define KCH   4
#define F_DIM 256   // B_DIM*CIN

// ---------------------------------------------------------------- utilities

__global__ __launch_bounds__(256) void zero_kernel(int* p, int n) {
    int i = blockIdx.x * 256 + threadIdx.x;
    if (i < n) p[i] = 0;
}

__global__ __launch_bounds__(256) void hist_kernel(const int* __restrict__ L_row,
                                                   int* __restrict__ cnt, int nnz) {
    int i = blockIdx.x * 256 + threadIdx.x;
    if (i < nnz) atomicAdd(&cnt[L_row[i]], 1);
}

// single-block exclusive scan over M counts; writes row_ptr[0..M] and
// resets cursor[i] = exclusive offset (for the scatter pass).
__global__ __launch_bounds__(1024) void scan_kernel(int* __restrict__ cursor,
                                                    int* __restrict__ row_ptr, int M) {
    __shared__ int wsum[16];
    __shared__ int sbase;
    int tid = threadIdx.x, lane = tid & 63, wid = tid >> 6;
    if (tid == 0) sbase = 0;
    __syncthreads();
    int nchunk = (M + 1023) / 1024;
    for (int ch = 0; ch < nchunk; ch++) {
        int i = ch * 1024 + tid;
        int cnt = (i < M) ? cursor[i] : 0;
        int v = cnt;
        #pragma unroll
        for (int d = 1; d < 64; d <<= 1) {
            int t = __shfl_up(v, d);
            if (lane >= d) v += t;
        }
        if (lane == 63) wsum[wid] = v;
        __syncthreads();
        if (wid == 0) {
            int w = (lane < 16) ? wsum[lane] : 0;
            #pragma unroll
            for (int d = 1; d < 16; d <<= 1) {
                int t = __shfl_up(w, d);
                if (lane >= d) w += t;
            }
            if (lane < 16) wsum[lane] = w;
        }
        __syncthreads();
        int base = sbase;
        int woff = (wid > 0) ? wsum[wid - 1] : 0;
        int excl = base + woff + (v - cnt);
        if (i < M) { row_ptr[i] = excl; cursor[i] = excl; }
        __syncthreads();
        if (tid == 0) sbase = base + wsum[15];
        __syncthreads();
    }
    if (threadIdx.x == 0) row_ptr[M] = sbase;
}

__global__ __launch_bounds__(256) void scatter_kernel(
        const int* __restrict__ L_row, const int* __restrict__ L_col,
        const float* __restrict__ L_val,
        int* __restrict__ cursor, int* __restrict__ csr_col,
        float* __restrict__ csr_val, int nnz) {
    int i = blockIdx.x * 256 + threadIdx.x;
    if (i < nnz) {
        int r = L_row[i];
        int p = atomicAdd(&cursor[r], 1);
        csr_col[p] = L_col[i];
        csr_val[p] = L_val[i];
    }
}

// theta (COUT,CIN,K) -> th_t[(k*CIN+i)*COUT + o]
__global__ __launch_bounds__(256) void th_prep_kernel(const float* __restrict__ theta,
                                                      float* __restrict__ th_t) {
    int idx = blockIdx.x * 256 + threadIdx.x;
    if (idx < KCH * CIN * COUT) {
        int o = idx & 63;
        int rest = idx >> 6;
        int i = rest & 31;
        int k = rest >> 5;
        th_t[idx] = theta[(o * CIN + i) * KCH + k];
    }
}

// x (256, M) -> X0 (M, 256): 64x64 LDS tile transpose
__global__ __launch_bounds__(256) void transpose_kernel(const float* __restrict__ x,
                                                        float* __restrict__ X0, int M) {
    __shared__ float tile[64][65];
    int tid = threadIdx.x;
    int ml = tid & 63;
    int fl0 = tid >> 6;               // 0..3
    int m0 = blockIdx.x * 64;
    int f0 = blockIdx.y * 64;
    #pragma unroll 4
    for (int ff = fl0; ff < 64; ff += 4) {
        int m = m0 + ml;
        tile[ff][ml] = (m < M) ? x[(size_t)(f0 + ff) * M + m] : 0.f;
    }
    __syncthreads();
    int fl = tid & 63;
    #pragma unroll 4
    for (int mm = fl0; mm < 64; mm += 4) {
        int m = m0 + mm;
        if (m < M) X0[(size_t)m * F_DIM + f0 + fl] = tile[fl][mm];
    }
}

// ---------------------------------------------------------------- SpMM core

// One wave gathers one CSR row: acc[f] = sum_e val[e]*Xin[col[e]][f],
// lane owns floats [lane*4, lane*4+4). 4-deep software pipeline.
__device__ __forceinline__ float4 gather_row(const int* __restrict__ col,
                                             const float* __restrict__ val,
                                             int start, int end,
                                             const float4* __restrict__ Xi4,
                                             int lane) {
    float4 acc = {0.f, 0.f, 0.f, 0.f};
    for (int base = start; base < end; base += 64) {
        int e = base + lane;
        int cl = 0; float vl = 0.f;
        if (e < end) { cl = col[e]; vl = val[e]; }
        int cnt = min(64, end - base);
        int c0 = __shfl(cl, 0), c1 = __shfl(cl, 1), c2 = __shfl(cl, 2), c3 = __shfl(cl, 3);
        float4 h0 = Xi4[(size_t)c0 * 64 + lane];
        float4 h1 = Xi4[(size_t)c1 * 64 + lane];
        float4 h2 = Xi4[(size_t)c2 * 64 + lane];
        float4 h3 = Xi4[(size_t)c3 * 64 + lane];
        for (int j = 0; j < cnt; j += 4) {
            float4 g0 = h0, g1 = h1, g2 = h2, g3 = h3;
            int jn = j + 4;
            if (jn < cnt) {
                int d0 = __shfl(cl, jn), d1 = __shfl(cl, jn + 1);
                int d2 = __shfl(cl, jn + 2), d3 = __shfl(cl, jn + 3);
                h0 = Xi4[(size_t)d0 * 64 + lane];
                h1 = Xi4[(size_t)d1 * 64 + lane];
                h2 = Xi4[(size_t)d2 * 64 + lane];
                h3 = Xi4[(size_t)d3 * 64 + lane];
            }
            float v0 = __shfl(vl, j),     v1 = __shfl(vl, j + 1);
            float v2 = __shfl(vl, j + 2), v3 = __shfl(vl, j + 3);
            acc.x += v0 * g0.x; acc.y += v0 * g0.y; acc.z += v0 * g0.z; acc.w += v0 * g0.w;
            acc.x += v1 * g1.x; acc.y += v1 * g1.y; acc.z += v1 * g1.z; acc.w += v1 * g1.w;
            acc.x += v2 * g2.x; acc.y += v2 * g2.y; acc.z += v2 * g2.z; acc.w += v2 * g2.w;
            acc.x += v3 * g3.x; acc.y += v3 * g3.y; acc.z += v3 * g3.z; acc.w += v3 * g3.w;
        }
    }
    return acc;
}

// MODE 1: Xout = L*Xin ; MODE 2: Xout = 2*L*Xin - Xprev
template <int MODE>
__global__ __launch_bounds__(256) void spmm_kernel(
        const int* __restrict__ row_ptr, const int* __restrict__ col,
        const float* __restrict__ val, const float* __restrict__ Xin,
        const float* __restrict__ Xprev, float* __restrict__ Xout, int M) {
    int lane = threadIdx.x & 63, wid = threadIdx.x >> 6;
    int m = blockIdx.x * 4 + wid;
    if (m >= M) return;
    int start = row_ptr[m], end = row_ptr[m + 1];
    float4 acc = gather_row(col, val, start, end, (const float4*)Xin, lane);
    float4 outv;
    if (MODE == 1) {
        outv = acc;
    } else {
        float4 p = ((const float4*)Xprev)[(size_t)m * 64 + lane];
        outv.x = 2.f * acc.x - p.x; outv.y = 2.f * acc.y - p.y;
        outv.z = 2.f * acc.z - p.z; outv.w = 2.f * acc.w - p.w;
    }
    ((float4*)Xout)[(size_t)m * 64 + lane] = outv;
}

// -------------------------------------------- fused SpMM3 + einsum + bias
// Block = 256 threads, 8 rows. Phase 1: each wave computes 2 rows of
// X3 = 2*L*X2 - X1 into LDS. Phase 2: y[b,o,m] = sum_k sum_i th[k][i][o]*Xk[m][b*32+i].
// Thread tile: r = tid&7 (node), og = (tid>>3)&7 (8 o's), bp = tid>>6 (2 b's).
__global__ __launch_bounds__(256) void spmm3_einsum_kernel(
        const int* __restrict__ row_ptr, const int* __restrict__ col,
        const float* __restrict__ val,
        const float* __restrict__ X0, const float* __restrict__ X1,
        const float* __restrict__ X2,
        const float* __restrict__ th_t, const float* __restrict__ bias,
        float* __restrict__ y, int M) {
    __shared__ __align__(16) float th_lds[KCH * CIN * COUT];  // 32 KB
    __shared__ __align__(16) float x_lds[8][260];
    __shared__ __align__(16) float x3_lds[8][260];

    int tid = threadIdx.x;
    int lane = tid & 63, wid = tid >> 6;

    for (int i = tid; i < KCH * CIN * COUT; i += 256) th_lds[i] = th_t[i];

    // ---- phase 1: gather X3 rows (2 per wave) into x3_lds
    const float4* X2_4 = (const float4*)X2;
    #pragma unroll
    for (int rr = 0; rr < 2; rr++) {
        int r = wid + rr * 4;
        int m = blockIdx.x * 8 + r;
        if (m < M) {
            int start = row_ptr[m], end = row_ptr[m + 1];
            float4 acc = gather_row(col, val, start, end, X2_4, lane);
            float4 p = ((const float4*)X1)[(size_t)m * 64 + lane];
            float4 x3;
            x3.x = 2.f * acc.x - p.x; x3.y = 2.f * acc.y - p.y;
            x3.z = 2.f * acc.z - p.z; x3.w = 2.f * acc.w - p.w;
            *(float4*)&x3_lds[r][lane * 4] = x3;
        }
    }

    // ---- phase 2: einsum
    int r  = tid & 7;
    int g  = tid >> 3;
    int og = g & 7;
    int bp = g >> 3;            // wave-uniform (== wid)
    int m  = blockIdx.x * 8 + r;

    float acc0[8] = {0.f, 0.f, 0.f, 0.f, 0.f, 0.f, 0.f, 0.f};
    float acc1[8] = {0.f, 0.f, 0.f, 0.f, 0.f, 0.f, 0.f, 0.f};

    for (int k = 0; k < KCH; k++) {
        const float* xr;
        if (k < 3) {
            const float* Xsrc = (k == 0) ? X0 : (k == 1) ? X1 : X2;
            const float4* Xs4 = (const float4*)Xsrc;
            __syncthreads();     // also covers x3_lds visibility (k==0 pass)
            #pragma unroll
            for (int q = 0; q < 2; q++) {
                int f4 = tid + q * 256;          // 0..511
                int rr2 = f4 >> 6, ff = f4 & 63;
                int mm = blockIdx.x * 8 + rr2;
                float4 v = {0.f, 0.f, 0.f, 0.f};
                if (mm < M) v = Xs4[(size_t)mm * 64 + ff];
                *(float4*)&x_lds[rr2][ff * 4] = v;
            }
            __syncthreads();
            xr = x_lds[r];
        } else {
            xr = x3_lds[r];
        }
        const float* thk = &th_lds[k * CIN * COUT];
        #pragma unroll
        for (int ci4 = 0; ci4 < 8; ci4++) {
            float4 xa = *(const float4*)&xr[(2 * bp) * CIN + ci4 * 4];
            float4 xb = *(const float4*)&xr[(2 * bp + 1) * CIN + ci4 * 4];
            float xav[4] = {xa.x, xa.y, xa.z, xa.w};
            float xbv[4] = {xb.x, xb.y, xb.z, xb.w};
            #pragma unroll
            for (int cc = 0; cc < 4; cc++) {
                const float* tp = &thk[(ci4 * 4 + cc) * COUT + og * 8];
                float4 t0 = *(const float4*)&tp[0];
                float4 t1 = *(const float4*)&tp[4];
                float a = xav[cc], b = xbv[cc];
                acc0[0] += a * t0.x; acc0[1] += a * t0.y; acc0[2] += a * t0.z; acc0[3] += a * t0.w;
                acc0[4] += a * t1.x; acc0[5] += a * t1.y; acc0[6] += a * t1.z; acc0[7] += a * t1.w;
                acc1[0] += b * t0.x; acc1[1] += b * t0.y; acc1[2] += b * t0.z; acc1[3] += b * t0.w;
                acc1[4] += b * t1.x; acc1[5] += b * t1.y; acc1[6] += b * t1.z; acc1[7] += b * t1.w;
            }
        }
    }

    if (m < M) {
        int b0 = 2 * bp, b1 = b0 + 1;
        #pragma unroll
        for (int oo = 0; oo < 8; oo++) {
            int o = og * 8 + oo;
            float bv = bias[o];
            y[(size_t)(b0 * COUT + o) * M + m] = acc0[oo] + bv;
            y[(size_t)(b1 * COUT + o) * M + m] = acc1[oo] + bv;
        }
    }
}

// ---------------------------------------------------------------- launcher

extern "C" void kernel_launch(void* const* d_in, const int* in_sizes, int n_in,
                              void* d_out, int out_size, void* d_ws, size_t ws_size,
                              hipStream_t stream) {
    const float* x     = (const float*)d_in[0];
    const int*   L_row = (const int*)d_in[1];
    const int*   L_col = (const int*)d_in[2];
    const float* L_val = (const float*)d_in[3];
    const float* theta = (const float*)d_in[4];
    const float* bias  = (const float*)d_in[5];
    float* y = (float*)d_out;

    int M   = in_sizes[0] / F_DIM;   // 100000
    int NNZ = in_sizes[1];           // 1600000

    // workspace layout (all rebuilt every call; ws poison is overwritten)
    size_t MF = (size_t)M * F_DIM;
    float* X0      = (float*)d_ws;
    float* X1      = X0 + MF;
    float* X2      = X1 + MF;
    float* th_t    = X2 + MF;                  // 8192 floats
    int*   row_ptr = (int*)(th_t + KCH * CIN * COUT);
    int*   cursor  = row_ptr + (M + 1);
    int*   csr_col = cursor + M;
    float* csr_val = (float*)(csr_col + NNZ);

    // CSR build
    zero_kernel<<<(M + 255) / 256, 256, 0, stream>>>(cursor, M);
    hist_kernel<<<(NNZ + 255) / 256, 256, 0, stream>>>(L_row, cursor, NNZ);
    scan_kernel<<<1, 1024, 0, stream>>>(cursor, row_ptr, M);
    scatter_kernel<<<(NNZ + 255) / 256, 256, 0, stream>>>(L_row, L_col, L_val,
                                                          cursor, csr_col, csr_val, NNZ);
    // theta re-layout
    th_prep_kernel<<<(KCH * CIN * COUT + 255) / 256, 256, 0, stream>>>(theta, th_t);
    // X0 = x^T
    transpose_kernel<<<dim3((M + 63) / 64, F_DIM / 64), 256, 0, stream>>>(x, X0, M);
    // X1 = L X0
    spmm_kernel<1><<<(M + 3) / 4, 256, 0, stream>>>(row_ptr, csr_col, csr_val,
                                                    X0, nullptr, X1, M);
    // X2 = 2 L X1 - X0
    spmm_kernel<2><<<(M + 3) / 4, 256, 0, stream>>>(row_ptr, csr_col, csr_val,
                                                    X1, X0, X2, M);
    // X3 = 2 L X2 - X1 fused with y = einsum + bias
    spmm3_einsum_kernel<<<(M + 7) / 8, 256, 0, stream>>>(row_ptr, csr_col, csr_val,
                                                         X0, X1, X2, th_t, bias, y, M);
}